// Round 9
// baseline (267.613 us; speedup 1.0000x reference)
//
#include <hip/hip_runtime.h>
#include <hip/hip_bf16.h>
#include <math.h>
#include <type_traits>

// ---------------------------------------------------------------------------
// SelfAttention B=4,T=2048,D=1024 fp32 in/out.
// Round 19: NO-LDS GEMM -- fragments loaded direct global->VGPR.
//   R13-R18 post-mortem: five structurally different staged-LDS kernels all
//   land 64-75us/dispatch (conflicts 0 or not, depth-1/2 prefetch, phase
//   pacing, -25% traffic). Per-block floor: div = 2470 cy/K-tile for ~600cy
//   of modeled work -> the staged-LDS + per-tile-sync family ITSELF is the
//   invariant. Leave the family.
//   Stripe layout property: a wave's MFMA fragment == one contiguous 1KB
//   unit, lane l owns bytes [16l,16l+16) == global_load_dwordx4. So load
//   fragments straight from L2 into VGPRs: no LDS, no DMA, no barriers, no
//   vmcnt drains. Cost: 2x L2 read traffic (no inter-wave sharing) -- L3
//   resident, ~25us at ~30TB/s vs 20.6us MFMA floor. Compiler pipelines
//   load->MFMA with its own counted vmcnt (m97 lesson); TLP 16 waves/CU.
// Geometry: 128x128 block, 4 waves (2x2 of 64x64), acc[2][2], 2-stage
// manual rotation (static names, rule #20). launch_bounds(256,4) caps
// VGPR at 128. Grids: proj (64,8,3), exp (16,16,4), div (16,8,4).
// Stripe layout (verified R13/R15): unit u=(r>>5)*(K>>4)+(k>>4), 512 els;
// el p=((r&31)+32*((k>>3)&1))*8+(k&7); lane l of a unit = row l&31,
// k-els (l>>5)*8..+8 = exact 32x32x16 A/B fragment slice.
// Accumulation order identical to R15-R18 -> absmax must stay 0.00048828.
// ---------------------------------------------------------------------------

typedef short shortx8 __attribute__((ext_vector_type(8)));
typedef short shortx4 __attribute__((ext_vector_type(4)));
typedef float floatx16 __attribute__((ext_vector_type(16)));

#define MODE_PROJ 0   // z=0,1: C=bf16(A B^T) striped;  z=2: Vt striped
#define MODE_EXP  1   // C = bf16(exp(alpha A B^T)) striped, rowsum += exp
#define MODE_DIV  2   // C = fp32(A B^T) / rowsum[row], row-major

// C[M,N] = f(A[M,K] @ B[N,K]^T). A,B striped (k-dim = K). z-batched.
// 128x128 tile, 4 waves: wm=(w>>1)*64, wn=(w&1)*64, acc[2][2].
template <int MODE>
__global__ __launch_bounds__(256, 4) void mfma_gemm_abt(
    const __hip_bfloat16* __restrict__ A, const __hip_bfloat16* __restrict__ B,
    void* __restrict__ Cv, float* __restrict__ rowsum,
    __hip_bfloat16* __restrict__ Vt,
    int M, int N, int K, long sA, long sB, long sC, float alpha)
{
    using CT = std::conditional_t<MODE == MODE_DIV, float, __hip_bfloat16>;

    const int z = blockIdx.z;
    A += (long)z * sA;
    B += (long)z * sB;
    CT* C = (CT*)Cv + (long)z * sC;

    const int t     = threadIdx.x;          // 0..255
    const int wave  = t >> 6;               // 0..3
    const int lane  = t & 63;
    const int m0    = blockIdx.x * 128;
    const int n0    = blockIdx.y * 128;
    const int wm    = (wave >> 1) * 64;     // 0,64
    const int wn    = (wave & 1) * 64;      // 0,64
    const int lrow  = lane & 31;            // col of C
    const int lhalf = lane >> 5;            // +4 rows in C

    // fragment source pointers: unit (rg, ku) at rg*KU*512 + ku*512.
    const long KU = (long)(K >> 4);
    const __hip_bfloat16* pA0 =
        A + (long)((m0 >> 5) + (wave >> 1) * 2 + 0) * KU * 512 + lane * 8;
    const __hip_bfloat16* pA1 =
        A + (long)((m0 >> 5) + (wave >> 1) * 2 + 1) * KU * 512 + lane * 8;
    const __hip_bfloat16* pB0 =
        B + (long)((n0 >> 5) + (wave & 1) * 2 + 0) * KU * 512 + lane * 8;
    const __hip_bfloat16* pB1 =
        B + (long)((n0 >> 5) + (wave & 1) * 2 + 1) * KU * 512 + lane * 8;

    floatx16 acc[2][2] = {};
    const int KUi = K >> 4;                 // 64 or 128, always even

    // 2-stage rotation, static register sets (rule #20).
    shortx8 x0a, x0b, y0a, y0b;             // set 0 (even ku)
    shortx8 x1a, x1b, y1a, y1b;             // set 1 (odd ku)

    x0a = *(const shortx8*)(pA0);
    x0b = *(const shortx8*)(pA1);
    y0a = *(const shortx8*)(pB0);
    y0b = *(const shortx8*)(pB1);

    for (int ku = 0; ku < KUi; ku += 2) {
        // load odd set (ku+1 always < KUi: KUi even)
        x1a = *(const shortx8*)(pA0 + (long)(ku + 1) * 512);
        x1b = *(const shortx8*)(pA1 + (long)(ku + 1) * 512);
        y1a = *(const shortx8*)(pB0 + (long)(ku + 1) * 512);
        y1b = *(const shortx8*)(pB1 + (long)(ku + 1) * 512);

        __builtin_amdgcn_s_setprio(1);
        acc[0][0] = __builtin_amdgcn_mfma_f32_32x32x16_bf16(x0a, y0a, acc[0][0], 0, 0, 0);
        acc[0][1] = __builtin_amdgcn_mfma_f32_32x32x16_bf16(x0a, y0b, acc[0][1], 0, 0, 0);
        acc[1][0] = __builtin_amdgcn_mfma_f32_32x32x16_bf16(x0b, y0a, acc[1][0], 0, 0, 0);
        acc[1][1] = __builtin_amdgcn_mfma_f32_32x32x16_bf16(x0b, y0b, acc[1][1], 0, 0, 0);
        __builtin_amdgcn_s_setprio(0);

        if (ku + 2 < KUi) {                 // load next even set
            x0a = *(const shortx8*)(pA0 + (long)(ku + 2) * 512);
            x0b = *(const shortx8*)(pA1 + (long)(ku + 2) * 512);
            y0a = *(const shortx8*)(pB0 + (long)(ku + 2) * 512);
            y0b = *(const shortx8*)(pB1 + (long)(ku + 2) * 512);
        }

        __builtin_amdgcn_s_setprio(1);
        acc[0][0] = __builtin_amdgcn_mfma_f32_32x32x16_bf16(x1a, y1a, acc[0][0], 0, 0, 0);
        acc[0][1] = __builtin_amdgcn_mfma_f32_32x32x16_bf16(x1a, y1b, acc[0][1], 0, 0, 0);
        acc[1][0] = __builtin_amdgcn_mfma_f32_32x32x16_bf16(x1b, y1a, acc[1][0], 0, 0, 0);
        acc[1][1] = __builtin_amdgcn_mfma_f32_32x32x16_bf16(x1b, y1b, acc[1][1], 0, 0, 0);
        __builtin_amdgcn_s_setprio(0);
    }

    // stripe store index for C striped with k-dim = N
    auto sidx = [&](int row, int col) -> long {
        return ((long)(row >> 5) * (N >> 4) + (col >> 4)) * 512
             + ((row & 31) + 32 * ((col >> 3) & 1)) * 8 + (col & 7);
    };

    // C/D layout (verified m74/m101): col = lane&31,
    // row = (reg&3) + 8*(reg>>2) + 4*(lane>>5),  reg in [0,16)
    if constexpr (MODE == MODE_PROJ) {
        if (z == 2) {
            // V -> Vt striped over (rows=d 1024, k=t 2048)
            const int bz   = m0 >> 11;          // batch = row / T
            const long bo2 = (long)bz * N * 2048;
            #pragma unroll
            for (int i = 0; i < 2; ++i)
                #pragma unroll
                for (int j = 0; j < 2; ++j)
                    #pragma unroll
                    for (int g = 0; g < 4; ++g) {
                        const int t0 = (m0 + wm + 32 * i + g * 8 + 4 * lhalf) & 2047;
                        const int d  = n0 + wn + 32 * j + lrow;
                        shortx4 pk;
                        #pragma unroll
                        for (int r = 0; r < 4; ++r) {
                            __hip_bfloat16 hb = __float2bfloat16(acc[i][j][4 * g + r]);
                            pk[r] = *(short*)&hb;
                        }
                        const long idx = bo2
                            + ((long)(d >> 5) * 128 + (t0 >> 4)) * 512
                            + ((d & 31) + 32 * ((t0 >> 3) & 1)) * 8 + (t0 & 7);
                        *(shortx4*)(Vt + idx) = pk;   // 4 consecutive t els
                    }
        } else {
            #pragma unroll
            for (int i = 0; i < 2; ++i)
                #pragma unroll
                for (int j = 0; j < 2; ++j)
                    #pragma unroll
                    for (int g = 0; g < 4; ++g)
                        #pragma unroll
                        for (int r = 0; r < 4; ++r) {
                            const int row = m0 + wm + 32 * i + g * 8 + 4 * lhalf + r;
                            const int col = n0 + wn + 32 * j + lrow;
                            C[sidx(row, col)] = __float2bfloat16(acc[i][j][4 * g + r]);
                        }
        }
    } else if constexpr (MODE == MODE_EXP) {
        #pragma unroll
        for (int i = 0; i < 2; ++i) {
            float rs[16];
            #pragma unroll
            for (int reg = 0; reg < 16; ++reg) rs[reg] = 0.0f;
            #pragma unroll
            for (int j = 0; j < 2; ++j)
                #pragma unroll
                for (int g = 0; g < 4; ++g)
                    #pragma unroll
                    for (int r = 0; r < 4; ++r) {
                        const int row = m0 + wm + 32 * i + g * 8 + 4 * lhalf + r;
                        const int col = n0 + wn + 32 * j + lrow;
                        const float e = __expf(acc[i][j][4 * g + r] * alpha);
                        rs[4 * g + r] += e;
                        C[sidx(row, col)] = __float2bfloat16(e);
                    }
            #pragma unroll
            for (int reg = 0; reg < 16; ++reg) {
                float v = rs[reg];
                v += __shfl_xor(v, 1);
                v += __shfl_xor(v, 2);
                v += __shfl_xor(v, 4);
                v += __shfl_xor(v, 8);
                v += __shfl_xor(v, 16);
                if (lrow == 0) {
                    const long row = m0 + wm + 32 * i + (reg >> 2) * 8 + 4 * lhalf + (reg & 3);
                    atomicAdd(&rowsum[(long)z * M + row], v);
                }
            }
        }
    } else {  // MODE_DIV: out row-major fp32
        #pragma unroll
        for (int i = 0; i < 2; ++i) {
            float inv[16];
            #pragma unroll
            for (int g = 0; g < 4; ++g)
                #pragma unroll
                for (int r = 0; r < 4; ++r) {
                    const long row = m0 + wm + 32 * i + g * 8 + 4 * lhalf + r;
                    inv[4 * g + r] = 1.0f / rowsum[(long)z * M + row];
                }
            #pragma unroll
            for (int j = 0; j < 2; ++j)
                #pragma unroll
                for (int g = 0; g < 4; ++g)
                    #pragma unroll
                    for (int r = 0; r < 4; ++r) {
                        const long row = m0 + wm + 32 * i + g * 8 + 4 * lhalf + r;
                        const long col = n0 + wn + 32 * j + lrow;
                        C[row * N + col] = acc[i][j][4 * g + r] * inv[4 * g + r];
                    }
        }
    }
}

// prep: cast x / Wq|Wk|Wv fp32->bf16 into stripe layout via LDS transpose.
// Block = one 32-row group x K=1024: coalesced float4 reads -> striped LDS
// image (64KB) -> 64KB CONTIGUOUS global write. Blocks 0..255: xb;
// 256..351: Wb. Blocks 0..31 also zero rowsum.
__global__ __launch_bounds__(256) void prep(
    const float* __restrict__ x,
    const float* __restrict__ W0, const float* __restrict__ W1,
    const float* __restrict__ W2,
    __hip_bfloat16* __restrict__ xb, __hip_bfloat16* __restrict__ Wb,
    float* __restrict__ rowsum)
{
    __shared__ __hip_bfloat16 sb[32768];    // 64KB striped image

    const int b  = blockIdx.x;
    const int tt = threadIdx.x;             // 0..255

    if (b < 32) {
        float4 zz; zz.x = zz.y = zz.z = zz.w = 0.0f;
        ((float4*)rowsum)[b * 256 + tt] = zz;
    }

    const float* src;
    __hip_bfloat16* dst;
    if (b < 256) {
        src = x + (long)b * 32 * 1024;
        dst = xb + (long)b * 32768;
    } else {
        const int w  = (b - 256) >> 5;
        const int rg = (b - 256) & 31;
        src = ((w == 0) ? W0 : (w == 1) ? W1 : W2) + (long)rg * 32 * 1024;
        dst = Wb + (long)w * 1048576 + (long)rg * 32768;
    }

    #pragma unroll
    for (int it = 0; it < 32; ++it) {
        const int idx4 = it * 256 + tt;         // float4 index in row-major
        const float4 f = ((const float4*)src)[idx4];
        const int row = idx4 >> 8;              // 256 float4 per row
        const int k0  = (idx4 & 255) << 2;
        const int p   = ((row & 31) + 32 * ((k0 >> 3) & 1)) * 8 + (k0 & 7);
        shortx4 pk;
        __hip_bfloat16 h0 = __float2bfloat16(f.x); pk[0] = *(short*)&h0;
        __hip_bfloat16 h1 = __float2bfloat16(f.y); pk[1] = *(short*)&h1;
        __hip_bfloat16 h2 = __float2bfloat16(f.z); pk[2] = *(short*)&h2;
        __hip_bfloat16 h3 = __float2bfloat16(f.w); pk[3] = *(short*)&h3;
        *(shortx4*)(sb + (k0 >> 4) * 512 + p) = pk;
    }
    __syncthreads();

    #pragma unroll
    for (int ot = 0; ot < 16; ++ot) {
        const int off = ot * 2048 + tt * 8;
        *(shortx8*)(dst + off) = *(const shortx8*)(sb + off);
    }
}

extern "C" void kernel_launch(void* const* d_in, const int* in_sizes, int n_in,
                              void* d_out, int out_size, void* d_ws, size_t ws_size,
                              hipStream_t stream)
{
    constexpr int  Bb = 4, T = 2048, D = 1024;
    constexpr int  M  = Bb * T;                 // 8192
    constexpr long TD = (long)T * D;            // 2,097,152
    constexpr long TT = (long)T * T;            // 4,194,304
    constexpr long MD = (long)M * D;            // 8,388,608

    const float* x  = (const float*)d_in[0];
    const float* Wq = (const float*)d_in[1];
    const float* Wk = (const float*)d_in[2];
    const float* Wv = (const float*)d_in[3];
    float* out = (float*)d_out;

    // workspace: Q|K|Vt (bf16 16MB each) | P (bf16 33.6MB) | xb (16MB)
    //            | Wb (6MB) | rowsum (32KB)   -> ~104 MB  (all striped)
    __hip_bfloat16* Q  = (__hip_bfloat16*)d_ws;
    __hip_bfloat16* Kb = Q + MD;
    __hip_bfloat16* Vt = Kb + MD;
    __hip_bfloat16* P  = Vt + MD;
    __hip_bfloat16* xb = P + (long)Bb * TT;
    __hip_bfloat16* Wb = xb + MD;
    float*     rowsum  = (float*)(Wb + 3L * D * D);

    prep<<<dim3(352), dim3(256), 0, stream>>>(x, Wq, Wk, Wv, xb, Wb, rowsum);

    dim3 blk(256);

    // projections: z=0 -> Q, z=1 -> K, z=2 -> Vt (striped)
    mfma_gemm_abt<MODE_PROJ><<<dim3(M / 128, D / 128, 3), blk, 0, stream>>>(
        xb, Wb, Q, nullptr, Vt, M, D, D, 0, (long)D * D, MD, 1.0f);

    // P = exp(Q K^T / 32) bf16 striped, rowsum via atomics
    mfma_gemm_abt<MODE_EXP><<<dim3(T / 128, T / 128, Bb), blk, 0, stream>>>(
        Q, Kb, P, rowsum, nullptr, T, T, D, TD, TD, TT, 0.03125f);

    // out = (P @ Vt^T) / rowsum[row]  (row-major fp32 output)
    mfma_gemm_abt<MODE_DIV><<<dim3(T / 128, D / 128, Bb), blk, 0, stream>>>(
        P, Vt, out, rowsum, nullptr, T, D, T, TT, TD, TD, 1.0f);

    (void)in_sizes; (void)n_in; (void)out_size; (void)ws_size;
}